// Round 1
// baseline (341.845 us; speedup 1.0000x reference)
//
#include <hip/hip_runtime.h>
#include <hip/hip_bf16.h>

#define NPTS  64
#define NCOLS 500000
#define NANG  2016   // 64*63/2

typedef __attribute__((ext_vector_type(8))) short bf16x8;
typedef __attribute__((ext_vector_type(4))) float f32x4;

static __device__ inline short f2bf(float f) {
    union { float f; unsigned u; } uf; uf.f = f;
    unsigned u = uf.u;
    // round-to-nearest-even bf16
    unsigned r = (u + 0x7fffu + ((u >> 16) & 1u)) >> 16;
    return (short)r;
}

// ---------------------------------------------------------------------------
// Kernel 1: build M = diag(mus) * (R_{K-1} ... R_1 R_0)  (64x64 fp32 -> d_ws)
// One wave; thread j owns column j of Q. The evolving iTop row lives in a
// register so the sequential dependence is a ~2016-FMA chain, not LDS
// round-trips.
// ---------------------------------------------------------------------------
__global__ __launch_bounds__(64) void build_M(const float* __restrict__ angles,
                                              const float* __restrict__ mus,
                                              float* __restrict__ Mout) {
    __shared__ float Q[NPTS][NPTS];   // Q[row][col], col == tid
    __shared__ float cs[NANG];
    __shared__ float sn[NANG];
    const int tid = threadIdx.x;

    for (int k = tid; k < NANG; k += 64) {
        float a = angles[k];
        cs[k] = cosf(a);
        sn[k] = sinf(a);
    }
    for (int r0 = 0; r0 < NPTS; ++r0)
        Q[r0][tid] = (r0 == tid) ? 1.0f : 0.0f;
    __syncthreads();

    float r = Q[0][tid];   // current iTop row value (this column)
    int k = 0;
    for (int i = 0; i < NPTS - 1; ++i) {
        for (int ib = i + 1; ib < NPTS; ++ib, ++k) {
            float c = cs[k], s = sn[k];
            float b = Q[ib][tid];
            Q[ib][tid] = s * r + c * b;   // uses OLD r (matches reference)
            r = c * r - s * b;
        }
        Q[i][tid] = r;           // row i is final
        r = Q[i + 1][tid];       // row i+1 was updated first in this block
    }
    __syncthreads();

    for (int row = 0; row < NPTS; ++row)
        Mout[row * NPTS + tid] = mus[row] * Q[row][tid];
}

// ---------------------------------------------------------------------------
// Kernel 2: out[64, NCOLS] = M[64,64] * X[64, NCOLS]  via bf16 MFMA.
// Each wave: M held as 8 A-frags in registers; grid-stride over 16-column
// stripes; X loaded straight from global in B-fragment order (4x64B fully
// used aligned segments per load), no LDS.
// ---------------------------------------------------------------------------
__global__ __launch_bounds__(256) void apply_M(const float* __restrict__ X,
                                               const float* __restrict__ M,
                                               float* __restrict__ out,
                                               int nstripes, int wstride) {
    const int lane  = threadIdx.x & 63;
    const int wave  = threadIdx.x >> 6;
    const int laneN = lane & 15;
    const int quad  = lane >> 4;

    // Build A fragments from M (fp32 -> bf16). A[m][k]: m = lane&15 (+16*t),
    // k = quad*8 + j (+32*q).
    bf16x8 afrag[4][2];
#pragma unroll
    for (int t = 0; t < 4; ++t) {
#pragma unroll
        for (int q = 0; q < 2; ++q) {
            const int m  = t * 16 + laneN;
            const int kb = q * 32 + quad * 8;
            const float* src = M + m * NPTS + kb;
            bf16x8 f;
#pragma unroll
            for (int j = 0; j < 8; ++j) f[j] = f2bf(src[j]);
            afrag[t][q] = f;
        }
    }

    const int gw = blockIdx.x * 4 + wave;
    for (int s = gw; s < nstripes; s += wstride) {
        const int col = s * 16 + laneN;
        const float* xb = X + col;

        // B fragments: B[k][n]: n = lane&15, k = quad*8 + j (+32*q)
        bf16x8 bfrag[2];
#pragma unroll
        for (int q = 0; q < 2; ++q) {
            const int kb = q * 32 + quad * 8;
            float v[8];
#pragma unroll
            for (int j = 0; j < 8; ++j) v[j] = xb[(kb + j) * NCOLS];
            bf16x8 f;
#pragma unroll
            for (int j = 0; j < 8; ++j) f[j] = f2bf(v[j]);
            bfrag[q] = f;
        }

#pragma unroll
        for (int t = 0; t < 4; ++t) {
            f32x4 acc = {0.f, 0.f, 0.f, 0.f};
            acc = __builtin_amdgcn_mfma_f32_16x16x32_bf16(afrag[t][0], bfrag[0], acc, 0, 0, 0);
            acc = __builtin_amdgcn_mfma_f32_16x16x32_bf16(afrag[t][1], bfrag[1], acc, 0, 0, 0);
            // C/D: col = lane&15, row = quad*4 + reg   [m89-verified]
#pragma unroll
            for (int rr = 0; rr < 4; ++rr) {
                const int row = t * 16 + quad * 4 + rr;
                out[row * NCOLS + col] = acc[rr];
            }
        }
    }
}

extern "C" void kernel_launch(void* const* d_in, const int* in_sizes, int n_in,
                              void* d_out, int out_size, void* d_ws, size_t ws_size,
                              hipStream_t stream) {
    const float* X      = (const float*)d_in[0];
    const float* angles = (const float*)d_in[1];
    const float* mus    = (const float*)d_in[2];
    float* out = (float*)d_out;
    float* M   = (float*)d_ws;   // 64*64*4 = 16 KB scratch

    build_M<<<1, 64, 0, stream>>>(angles, mus, M);

    const int nstripes = NCOLS / 16;       // 31250
    const int blocks   = 1024;             // 4096 waves, 16 waves/CU
    apply_M<<<blocks, 256, 0, stream>>>(X, M, out, nstripes, blocks * 4);
}

// Round 2
// 322.304 us; speedup vs baseline: 1.0606x; 1.0606x over previous
//
#include <hip/hip_runtime.h>
#include <hip/hip_bf16.h>

#define NPTS  64
#define NCOLS 500000
#define NANG  2016   // 64*63/2

typedef __attribute__((ext_vector_type(8))) short bf16x8;
typedef __attribute__((ext_vector_type(4))) float f32x4;

static __device__ inline short f2bf(float f) {
    union { float f; unsigned u; } uf; uf.f = f;
    unsigned u = uf.u;
    // round-to-nearest-even bf16
    unsigned r = (u + 0x7fffu + ((u >> 16) & 1u)) >> 16;
    return (short)r;
}

// ---------------------------------------------------------------------------
// Kernel 1: build M = diag(mus) * (R_{K-1} ... R_1 R_0)  (64x64 fp32 -> d_ws)
// One wave; thread j owns column j of Q, held ENTIRELY IN REGISTERS via full
// unroll (static indices). Critical path = 2016-deep dependent FMA chain
// (~8k cycles), no LDS round-trips in the chain. c/s are broadcast LDS reads.
// ---------------------------------------------------------------------------
__global__ __launch_bounds__(64) void build_M(const float* __restrict__ angles,
                                              const float* __restrict__ mus,
                                              float* __restrict__ Mout) {
    __shared__ float cs[NANG];
    __shared__ float sn[NANG];
    const int tid = threadIdx.x;

    for (int k = tid; k < NANG; k += 64) {
        float a = angles[k];
        cs[k] = cosf(a);
        sn[k] = sinf(a);
    }
    __syncthreads();

    float q[NPTS];
#pragma unroll
    for (int j = 0; j < NPTS; ++j) q[j] = (j == tid) ? 1.0f : 0.0f;

    int k = 0;
#pragma unroll
    for (int i = 0; i < NPTS - 1; ++i) {
#pragma unroll
        for (int ib = i + 1; ib < NPTS; ++ib, ++k) {
            float c = cs[k], s = sn[k];
            float t = q[i];
            float b = q[ib];
            q[ib] = s * t + c * b;   // uses OLD q[i] (matches reference)
            q[i]  = c * t - s * b;
        }
    }

#pragma unroll
    for (int row = 0; row < NPTS; ++row)
        Mout[row * NPTS + tid] = mus[row] * q[row];
}

// ---------------------------------------------------------------------------
// Kernel 2: out[64, NCOLS] = M[64,64] * X[64, NCOLS]  via bf16 MFMA.
// 64-column stripes per wave, dwordx4 loads/stores. Column permutation trick:
// float4 element e of lane n feeds MFMA tile u=e at B-index n (tile u covers
// physical cols S+4n+u); the output permutes identically, so the 4 per-tile
// accumulators reassemble into a contiguous float4 store. No shuffles.
// ---------------------------------------------------------------------------
__global__ __launch_bounds__(256) void apply_M(const float* __restrict__ X,
                                               const float* __restrict__ M,
                                               float* __restrict__ out,
                                               int nfull, int wstride) {
    const int lane  = threadIdx.x & 63;
    const int wave  = threadIdx.x >> 6;
    const int laneN = lane & 15;
    const int quad  = lane >> 4;

    // A fragments from M (fp32 -> bf16). A[m][k]: m = lane&15 (+16t),
    // k = quad*8 + j (+32q).   [verified correct in round 1]
    bf16x8 afrag[4][2];
#pragma unroll
    for (int t = 0; t < 4; ++t) {
#pragma unroll
        for (int q = 0; q < 2; ++q) {
            const float* src = M + (t * 16 + laneN) * NPTS + q * 32 + quad * 8;
            bf16x8 f;
#pragma unroll
            for (int j = 0; j < 8; ++j) f[j] = f2bf(src[j]);
            afrag[t][q] = f;
        }
    }

    const int gw = blockIdx.x * 4 + wave;

    for (int s = gw; s < nfull; s += wstride) {
        const long col0 = (long)s * 64 + 4 * laneN;
        const float* xb = X + col0;

        // B fragments for 4 tiles: tile u, B_u[k][n] = X[k][S + 4n + u]
        bf16x8 bfrag[4][2];
#pragma unroll
        for (int q = 0; q < 2; ++q) {
#pragma unroll
            for (int j = 0; j < 8; ++j) {
                const int kk = q * 32 + quad * 8 + j;
                f32x4 v = *(const f32x4*)(xb + (long)kk * NCOLS);
#pragma unroll
                for (int u = 0; u < 4; ++u)
                    bfrag[u][q][j] = f2bf(v[u]);
            }
        }

#pragma unroll
        for (int t = 0; t < 4; ++t) {
            f32x4 acc[4];
#pragma unroll
            for (int u = 0; u < 4; ++u) {
                f32x4 a = {0.f, 0.f, 0.f, 0.f};
                a = __builtin_amdgcn_mfma_f32_16x16x32_bf16(afrag[t][0], bfrag[u][0], a, 0, 0, 0);
                a = __builtin_amdgcn_mfma_f32_16x16x32_bf16(afrag[t][1], bfrag[u][1], a, 0, 0, 0);
                acc[u] = a;
            }
            // D: col = S + 4*laneN + u, row = t*16 + quad*4 + rr
#pragma unroll
            for (int rr = 0; rr < 4; ++rr) {
                const int row = t * 16 + quad * 4 + rr;
                f32x4 o = { acc[0][rr], acc[1][rr], acc[2][rr], acc[3][rr] };
                *(f32x4*)(out + (long)row * NCOLS + col0) = o;
            }
        }
    }

    // Tail: NCOLS - nfull*64 = 32 columns, two 16-col stripes (round-1 path)
    if (gw < 2) {
        const int col = nfull * 64 + gw * 16 + laneN;
        const float* xb = X + col;
        bf16x8 bfrag[2];
#pragma unroll
        for (int q = 0; q < 2; ++q) {
            bf16x8 f;
#pragma unroll
            for (int j = 0; j < 8; ++j)
                f[j] = f2bf(xb[(long)(q * 32 + quad * 8 + j) * NCOLS]);
            bfrag[q] = f;
        }
#pragma unroll
        for (int t = 0; t < 4; ++t) {
            f32x4 a = {0.f, 0.f, 0.f, 0.f};
            a = __builtin_amdgcn_mfma_f32_16x16x32_bf16(afrag[t][0], bfrag[0], a, 0, 0, 0);
            a = __builtin_amdgcn_mfma_f32_16x16x32_bf16(afrag[t][1], bfrag[1], a, 0, 0, 0);
#pragma unroll
            for (int rr = 0; rr < 4; ++rr)
                out[(long)(t * 16 + quad * 4 + rr) * NCOLS + col] = a[rr];
        }
    }
}

extern "C" void kernel_launch(void* const* d_in, const int* in_sizes, int n_in,
                              void* d_out, int out_size, void* d_ws, size_t ws_size,
                              hipStream_t stream) {
    const float* X      = (const float*)d_in[0];
    const float* angles = (const float*)d_in[1];
    const float* mus    = (const float*)d_in[2];
    float* out = (float*)d_out;
    float* M   = (float*)d_ws;   // 64*64*4 = 16 KB scratch

    build_M<<<1, 64, 0, stream>>>(angles, mus, M);

    const int nfull  = NCOLS / 64;   // 7812 full 64-col stripes (+32 tail)
    const int blocks = 1024;         // 4096 waves, 16 waves/CU
    apply_M<<<blocks, 256, 0, stream>>>(X, M, out, nfull, blocks * 4);
}